// Round 2
// baseline (306.682 us; speedup 1.0000x reference)
//
#include <hip/hip_runtime.h>
#include <hip/hip_bf16.h>

#define B_    4
#define NUM   1024
#define CH    256
#define HEADS 4
#define DK    64
#define LDK   72   // padded LDS row stride in bf16 elements (2-way bank alias = free)
#define NJC   4    // j-chunks per (b,h,i-tile) in score kernel; chunk = 256 cols

typedef __hip_bfloat16 bf;
typedef __attribute__((ext_vector_type(8))) short short8;
typedef __attribute__((ext_vector_type(4))) float f32x4;
typedef unsigned long long u64;

#define SEG_ ((size_t)B_ * NUM * CH)   // 1048576 elements

__device__ inline bf tobf(float v) { return __float2bfloat16(v); }

// stage a 64x64 fp32 global tile -> bf16 LDS tile (convert path, gts only)
__device__ inline void stage_tile(const float* __restrict__ src, size_t row0,
                                  int col0, int rowstride, bf (*dst)[LDK], int tid) {
  int r = tid >> 4, c4 = (tid & 15) * 4;
  #pragma unroll
  for (int it = 0; it < 4; ++it) {
    int row = r + it * 16;
    const float4 v = *(const float4*)&src[(row0 + row) * (size_t)rowstride + col0 + c4];
    union { bf h4[4]; short4 s4; } u;
    u.h4[0] = tobf(v.x); u.h4[1] = tobf(v.y); u.h4[2] = tobf(v.z); u.h4[3] = tobf(v.w);
    *(short4*)&dst[row][c4] = u.s4;
  }
}

// load this lane's A-fragments straight from the bf16 copy (two 16B loads)
__device__ inline void load_afrag_bf(const bf* __restrict__ arow, int quad, short8 af[2]) {
  af[0] = *(const short8*)&arow[quad * 8];
  af[1] = *(const short8*)&arow[32 + quad * 8];
}

// ---------------- conv body: grouped 1x1 conv + relu, dual write + rn + bf16 x-copy ----------------
__device__ inline void conv_body(
    char* SM, int m0, int g, int tid,
    const float* __restrict__ x, const float* __restrict__ w,
    const float* __restrict__ bias, const int* __restrict__ smask,
    float seedbase, float* __restrict__ out, float* __restrict__ out2,
    float* __restrict__ rn, bf* __restrict__ xbf) {
  float (*Xs)[65] = (float(*)[65])SM;
  float (*Wsm)[65] = (float(*)[65])(SM + 16640);
  const int tx = tid & 15, ty = tid >> 4;
  #pragma unroll
  for (int l = 0; l < 16; ++l) {
    int idx = tid + l * 256; int r = idx >> 6, c = idx & 63;
    Xs[r][c] = x[(size_t)(m0 + r) * CH + g * DK + c];
    Wsm[r][c] = w[g * DK * DK + r * DK + c];
  }
  __syncthreads();
  {  // bf16 copy of the input slice (node-major) for score staging
    int r = tid >> 4, c4 = (tid & 15) * 4;
    #pragma unroll
    for (int it = 0; it < 4; ++it) {
      int row = r + it * 16;
      union { bf h4[4]; short4 s4; } u;
      u.h4[0] = tobf(Xs[row][c4]);     u.h4[1] = tobf(Xs[row][c4 + 1]);
      u.h4[2] = tobf(Xs[row][c4 + 2]); u.h4[3] = tobf(Xs[row][c4 + 3]);
      *(short4*)&xbf[(size_t)(m0 + row) * CH + g * DK + c4] = u.s4;
    }
  }
  {  // fused reciprocal norms: 4 lanes per row, 16 channels each
    int wv = tid >> 6, lane = tid & 63;
    int row = wv * 16 + (lane >> 2), part = lane & 3;
    float s = 0.f;
    #pragma unroll
    for (int k = 0; k < 16; ++k) {
      float v = Xs[row][part * 16 + k];
      s += v * v;
    }
    s += __shfl_xor(s, 1, 64);
    s += __shfl_xor(s, 2, 64);
    if (part == 0)
      rn[(size_t)(m0 + row) * HEADS + g] = 1.0f / fmaxf(sqrtf(s), 1e-4f);
  }
  float acc[4][4] = {};
  #pragma unroll 8
  for (int k = 0; k < DK; ++k) {
    float av[4], bv[4];
    #pragma unroll
    for (int i = 0; i < 4; ++i) av[i] = Xs[ty * 4 + i][k];
    #pragma unroll
    for (int j = 0; j < 4; ++j) bv[j] = Wsm[tx * 4 + j][k];
    #pragma unroll
    for (int i = 0; i < 4; ++i)
      #pragma unroll
      for (int j = 0; j < 4; ++j) acc[i][j] += av[i] * bv[j];
  }
  #pragma unroll
  for (int i = 0; i < 4; ++i) {
    int row = m0 + ty * 4 + i;
    float seed = seedbase + ((smask[row] == 0) ? 0.25f : 0.f);
    #pragma unroll
    for (int j = 0; j < 4; ++j) {
      int o = g * DK + tx * 4 + j;
      size_t idx = (size_t)row * CH + o;
      float v = fmaxf(acc[i][j] + bias[o], 0.f);
      out[idx] = v;
      out2[idx] = v * seed;
    }
  }
}

// ---------------- gts body: relu(gt_feat @ gt_w^T + gt_b), bf16 MFMA ----------------
__device__ inline void gts_body(
    char* SM, int m0, int n0, int tid,
    const float* __restrict__ gf, const float* __restrict__ gw,
    const float* __restrict__ gb, float* __restrict__ out) {
  bf (*As)[LDK] = (bf(*)[LDK])SM;
  bf (*Bs)[LDK] = (bf(*)[LDK])(SM + 9216);
  const int lane = tid & 63, w = tid >> 6;
  const int m = lane & 15, quad = lane >> 4;
  f32x4 acc[4] = {{0.f,0.f,0.f,0.f},{0.f,0.f,0.f,0.f},{0.f,0.f,0.f,0.f},{0.f,0.f,0.f,0.f}};
  for (int k0 = 0; k0 < 256; k0 += 64) {
    __syncthreads();
    stage_tile(gf, m0, k0, 256, As, tid);
    stage_tile(gw, n0, k0, 256, Bs, tid);
    __syncthreads();
    #pragma unroll
    for (int kb = 0; kb < 2; ++kb) {
      short8 a = *(const short8*)&As[w * 16 + m][kb * 32 + quad * 8];
      #pragma unroll
      for (int nt = 0; nt < 4; ++nt) {
        short8 bb = *(const short8*)&Bs[nt * 16 + m][kb * 32 + quad * 8];
        acc[nt] = __builtin_amdgcn_mfma_f32_16x16x32_bf16(a, bb, acc[nt], 0, 0, 0);
      }
    }
  }
  #pragma unroll
  for (int nt = 0; nt < 4; ++nt)
    #pragma unroll
    for (int r = 0; r < 4; ++r) {
      int row = m0 + w * 16 + quad * 4 + r, col = n0 + nt * 16 + m;
      out[(size_t)row * 256 + col] = fmaxf(acc[nt][r] + gb[col], 0.f);
    }
}

// ================ mega head kernel: conv1 (y<4) | gts (y 4..7) | pack (y 8..23) ================
__global__ __launch_bounds__(256) void head_kernel(
    const float* __restrict__ x, const float* __restrict__ w1,
    const float* __restrict__ b1, const int* __restrict__ smask,
    float* __restrict__ X1, float* __restrict__ F1, float* __restrict__ rn,
    bf* __restrict__ xbf,
    const float* __restrict__ gf, const float* __restrict__ gw,
    const float* __restrict__ gb, float* __restrict__ gts_out,
    const int* __restrict__ mroi, u64* __restrict__ pk,
    float* __restrict__ v1, float* __restrict__ v2) {
  __shared__ __align__(16) char SM[33280];
  const int tid = threadIdx.x;
  if (blockIdx.y < 4) {
    conv_body(SM, blockIdx.x * 64, blockIdx.y, tid, x, w1, b1, smask, 1.0f, X1, F1, rn, xbf);
  } else if (blockIdx.y < 8) {
    gts_body(SM, blockIdx.x * 64, (blockIdx.y - 4) * 64, tid, gf, gw, gb, gts_out);
  } else {
    int blkrow = (blockIdx.y - 8) * 64 + blockIdx.x;   // 0..1023
    if (blkrow < 4) {
      int i = blkrow * 256 + tid;
      v1[i] = 0.f; v2[i] = 0.f;
    }
    int row = blkrow * 4 + (tid >> 6);
    int lane = tid & 63;
    int b = row >> 10;
    const int* mr = &mroi[(size_t)row * NUM];
    const int* sm = &smask[b * NUM];
    #pragma unroll
    for (int wd = 0; wd < 16; ++wd) {
      int j = wd * 64 + lane;
      u64 word = __ballot((mr[j] != 0) && (sm[j] != 0));
      if (lane == 0) pk[(size_t)row * 16 + wd] = word;
    }
  }
}

// ---------------- grouped 1x1 conv + relu (fp32) standalone (stage 2) ----------------
__global__ __launch_bounds__(256) void conv_kernel(
    const float* __restrict__ x, const float* __restrict__ w,
    const float* __restrict__ bias, const int* __restrict__ smask,
    float seedbase, float* __restrict__ out, float* __restrict__ out2,
    float* __restrict__ rn, bf* __restrict__ xbf) {
  __shared__ __align__(16) char SM[33280];
  conv_body(SM, blockIdx.x * 64, blockIdx.y, threadIdx.x, x, w, bias, smask,
            seedbase, out, out2, rn, xbf);
}

// top-4 insert, jax-stable tie-break (higher value first; equal value -> lower index)
__device__ inline void ins4(float v, int id, float tv[4], int tj[4]) {
  if (v < tv[3] || (v == tv[3] && id > tj[3])) return;
  tv[3] = v; tj[3] = id;
  #pragma unroll
  for (int k = 3; k > 0; --k) {
    bool sw = (tv[k] > tv[k - 1]) || (tv[k] == tv[k - 1] && tj[k] < tj[k - 1]);
    if (sw) {
      float fv = tv[k]; tv[k] = tv[k - 1]; tv[k - 1] = fv;
      int ti = tj[k]; tj[k] = tj[k - 1]; tj[k - 1] = ti;
    }
  }
}

// ---------------- fused scores + top-4 (scores computed ONCE per stage) ----------------
// Computes the 64x256 score tile for (b,h,it,jc) with MFMA B-frags loaded DIRECTLY
// from global xbf (no LDS, no barriers). Writes pk-masked relu scores (bf16) to the
// WS scratch [b][h][i][j] for the pv kernel, and per-row top-4 candidates (ranking on
// relu(dot*rnj), identical order to relu(dot/(ni*nj))). Row-merge across the 16
// m-lanes is a shfl_xor butterfly (replaces the old serial single-wave LDS merge).
__global__ __launch_bounds__(256) void score_topk_kernel(
    const bf* __restrict__ xbf, const float* __restrict__ rn,
    const u64* __restrict__ pk, bf* __restrict__ wsout,
    float* __restrict__ candV, int* __restrict__ candI) {
  const int b = blockIdx.z, h = blockIdx.y;
  const int it = blockIdx.x >> 2, jc = blockIdx.x & 3;
  const int i0 = it * 64;
  const int tid = threadIdx.x, lane = tid & 63, w = tid >> 6;
  const int m = lane & 15, quad = lane >> 4;

  short8 afrag[2];
  load_afrag_bf(&xbf[((size_t)b * NUM + i0 + w * 16 + m) * CH + h * DK], quad, afrag);

  float tv[4][4]; int tj[4][4];
  #pragma unroll
  for (int r = 0; r < 4; ++r)
    #pragma unroll
    for (int q = 0; q < 4; ++q) { tv[r][q] = -1.f; tj[r][q] = 0xffff; }

  const size_t wsrow0 = (size_t)(b * HEADS + h) * NUM + i0 + w * 16 + quad * 4;

  #pragma unroll 2
  for (int jt = 0; jt < 4; ++jt) {
    const int j0 = jc * 256 + jt * 64;
    u64 wr[4];
    #pragma unroll
    for (int r = 0; r < 4; ++r)
      wr[r] = pk[((size_t)b * NUM + i0 + w * 16 + quad * 4 + r) * 16 + (j0 >> 6)];
    #pragma unroll
    for (int nt = 0; nt < 4; ++nt) {
      f32x4 acc = {0.f, 0.f, 0.f, 0.f};
      #pragma unroll
      for (int kb = 0; kb < 2; ++kb) {
        short8 bb = *(const short8*)
            &xbf[((size_t)b * NUM + j0 + nt * 16 + m) * CH + h * DK + kb * 32 + quad * 8];
        acc = __builtin_amdgcn_mfma_f32_16x16x32_bf16(afrag[kb], bb, acc, 0, 0, 0);
      }
      const int j = j0 + nt * 16 + m;
      const float rnj = rn[((size_t)b * NUM + j) * HEADS + h];
      #pragma unroll
      for (int r = 0; r < 4; ++r) {
        float rel = fmaxf(acc[r], 0.f);
        ins4(rel * rnj, j, tv[r], tj[r]);
        bool bit = (wr[r] >> (nt * 16 + m)) & 1ull;
        wsout[(wsrow0 + r) * NUM + j] = tobf(bit ? rel : 0.f);
      }
    }
  }
  // butterfly merge of top-4 lists across the 16 m-lanes of each quad group
  #pragma unroll
  for (int st = 1; st < 16; st <<= 1) {
    #pragma unroll
    for (int r = 0; r < 4; ++r) {
      float ov[4]; int oj[4];
      #pragma unroll
      for (int q = 0; q < 4; ++q) {
        ov[q] = __shfl_xor(tv[r][q], st, 64);
        oj[q] = __shfl_xor(tj[r][q], st, 64);
      }
      #pragma unroll
      for (int q = 0; q < 4; ++q) ins4(ov[q], oj[q], tv[r], tj[r]);
    }
  }
  if (m == 0) {
    #pragma unroll
    for (int r = 0; r < 4; ++r) {
      int rl = w * 16 + quad * 4 + r;
      size_t base = (size_t)((((b * HEADS + h) * 16 + it) * NJC + jc) * 64 + rl) * 4;
      #pragma unroll
      for (int q = 0; q < 4; ++q) { candV[base + q] = tv[r][q]; candI[base + q] = tj[r][q]; }
    }
  }
}

// ---------------- merge NJC chunk candidates per row -> union into vec ----------------
__global__ __launch_bounds__(256) void topk_merge_kernel(
    const float* __restrict__ candV, const int* __restrict__ candI,
    float* __restrict__ vec) {
  int t = blockIdx.x * 256 + threadIdx.x;   // t = bhit*64 + rl
  int bhit = t >> 6, rl = t & 63;
  float fv[4] = {-1.f, -1.f, -1.f, -1.f};
  int fi[4] = {0x7fffffff, 0x7fffffff, 0x7fffffff, 0x7fffffff};
  #pragma unroll
  for (int jc = 0; jc < NJC; ++jc) {
    size_t base = (size_t)(((bhit) * NJC + jc) * 64 + rl) * 4;
    #pragma unroll
    for (int q = 0; q < 4; ++q) ins4(candV[base + q], candI[base + q], fv, fi);
  }
  #pragma unroll
  for (int q = 0; q < 4; ++q) vec[fi[q]] = 1.0f;  // benign race, all write 1
}

// ---------------- PV apply: om = Ws(scratch) @ Cv, exclusive tiles, no atomics ----------------
// Block (it,h,b) owns i-rows [i0,i0+64) x channels [h*DK, h*DK+64): writes are exclusive.
// A-frags stream straight from the WS scratch (prefetched 1 tile ahead in regs);
// Cv (conv^T scaled by vec*rnj, bf16) is issue-early/write-late double-buffered in LDS.
__global__ __launch_bounds__(256) void pv_kernel(
    const bf* __restrict__ wsin, const float* __restrict__ conv,
    const float* __restrict__ rn, const float* __restrict__ vec,
    float* __restrict__ out) {
  __shared__ __align__(16) bf Cv[2][64][LDK];
  const int b = blockIdx.z, h = blockIdx.y, it = blockIdx.x;
  const int i0 = it * 64;
  const int tid = threadIdx.x, lane = tid & 63, w = tid >> 6;
  const int m = lane & 15, quad = lane >> 4;
  const int jr = tid >> 4, c4 = tid & 15;

  float rni4[4];
  #pragma unroll
  for (int r = 0; r < 4; ++r)
    rni4[r] = 0.25f * rn[((size_t)b * NUM + i0 + w * 16 + quad * 4 + r) * HEADS + h];

  const size_t wsrow = ((size_t)(b * HEADS + h) * NUM + i0 + w * 16 + m) * NUM;

  f32x4 om[4] = {{0.f,0.f,0.f,0.f},{0.f,0.f,0.f,0.f},{0.f,0.f,0.f,0.f},{0.f,0.f,0.f,0.f}};

  float4 pre[4]; float psc[4];
  // --- issue global loads of Cv tile jt ---
  auto issue = [&](int jt) {
    #pragma unroll
    for (int itt = 0; itt < 4; ++itt) {
      int j = jt * 64 + jr + itt * 16;
      psc[itt] = vec[j] * rn[((size_t)b * NUM + j) * HEADS + h];
      pre[itt] = *(const float4*)&conv[((size_t)b * NUM + j) * CH + h * DK + c4 * 4];
    }
  };
  // --- convert + write staged regs into LDS buffer ---
  auto lwrite = [&](int buf) {
    #pragma unroll
    for (int itt = 0; itt < 4; ++itt) {
      int j = jr + itt * 16;
      Cv[buf][c4 * 4 + 0][j] = tobf(pre[itt].x * psc[itt]);
      Cv[buf][c4 * 4 + 1][j] = tobf(pre[itt].y * psc[itt]);
      Cv[buf][c4 * 4 + 2][j] = tobf(pre[itt].z * psc[itt]);
      Cv[buf][c4 * 4 + 3][j] = tobf(pre[itt].w * psc[itt]);
    }
  };

  issue(0); lwrite(0);
  short8 a0 = *(const short8*)&wsin[wsrow + quad * 8];
  short8 a1 = *(const short8*)&wsin[wsrow + 32 + quad * 8];

  for (int jt = 0; jt < 16; ++jt) {
    const int cur = jt & 1;
    short8 na0, na1;
    if (jt < 15) {
      issue(jt + 1);   // global loads in flight across the MFMA phase
      na0 = *(const short8*)&wsin[wsrow + (jt + 1) * 64 + quad * 8];
      na1 = *(const short8*)&wsin[wsrow + (jt + 1) * 64 + 32 + quad * 8];
    }
    __syncthreads();   // Cv[cur] fully written; prior readers of Cv[cur^1] done
    #pragma unroll
    for (int ct = 0; ct < 4; ++ct)
      om[ct] = __builtin_amdgcn_mfma_f32_16x16x32_bf16(
          a0, *(const short8*)&Cv[cur][ct * 16 + m][quad * 8], om[ct], 0, 0, 0);
    #pragma unroll
    for (int ct = 0; ct < 4; ++ct)
      om[ct] = __builtin_amdgcn_mfma_f32_16x16x32_bf16(
          a1, *(const short8*)&Cv[cur][ct * 16 + m][32 + quad * 8], om[ct], 0, 0, 0);
    if (jt < 15) lwrite(cur ^ 1);
    a0 = na0; a1 = na1;
  }

  #pragma unroll
  for (int ct = 0; ct < 4; ++ct)
    #pragma unroll
    for (int r = 0; r < 4; ++r) {
      size_t idx = ((size_t)b * NUM + i0 + w * 16 + quad * 4 + r) * CH + h * DK + ct * 16 + m;
      out[idx] += om[ct][r] * rni4[r];   // exclusive tile: plain RMW
    }
}

// ---------------- LayerNorm + final outputs (in-place on d_out regions) ----------------
__global__ __launch_bounds__(256) void final_kernel(
    float* __restrict__ ybnf, float* __restrict__ out0,
    const float* __restrict__ lnw, const float* __restrict__ lnb) {
  __shared__ float r1[4];
  __shared__ float r2[4];
  int bn = blockIdx.x;
  int c = threadIdx.x;
  size_t idx = (size_t)bn * CH + c;
  float y = ybnf[idx];
  float x2v = out0[idx];
  float s = y;
  #pragma unroll
  for (int off = 32; off; off >>= 1) s += __shfl_down(s, off, 64);
  int wave = c >> 6, lane = c & 63;
  if (lane == 0) r1[wave] = s;
  __syncthreads();
  float mu = (r1[0] + r1[1] + r1[2] + r1[3]) * (1.f / 256.f);
  float d = y - mu;
  float s2 = d * d;
  #pragma unroll
  for (int off = 32; off; off >>= 1) s2 += __shfl_down(s2, off, 64);
  if (lane == 0) r2[wave] = s2;
  __syncthreads();
  float var = (r2[0] + r2[1] + r2[2] + r2[3]) * (1.f / 256.f);
  float nf = d * rsqrtf(var + 1e-6f) * lnw[c] + lnb[c];
  ybnf[idx] = nf;
  out0[idx] = x2v + nf;
}

extern "C" void kernel_launch(void* const* d_in, const int* in_sizes, int n_in,
                              void* d_out, int out_size, void* d_ws, size_t ws_size,
                              hipStream_t stream) {
  const float* input = (const float*)d_in[0];
  const int* mroi = (const int*)d_in[1];
  const int* smask = (const int*)d_in[2];
  const float* gt_feat = (const float*)d_in[3];
  const float* w1 = (const float*)d_in[4];
  const float* b1 = (const float*)d_in[5];
  const float* w2 = (const float*)d_in[6];
  const float* b2 = (const float*)d_in[7];
  const float* gt_w = (const float*)d_in[8];
  const float* gt_b = (const float*)d_in[9];
  const float* lnw = (const float*)d_in[10];
  const float* lnb = (const float*)d_in[11];

  const size_t SEG = SEG_;         // 1048576 elements
  float* out0 = (float*)d_out;     // finally: out2^T + node_feat ; interim: X2 (conv2)
  float* gts = out0 + SEG;         // gts output (final from the start)
  float* nfreg = out0 + 2 * SEG;   // finally: node_feat ; interim: X1 then Yb

  // ws: F1 4MB | RN 64KB | VEC 8KB | candV 4MB | candI 4MB | PK 512KB | XBF 2MB | WS 32MB
  float* F1 = (float*)d_ws;
  float* RN = F1 + SEG;
  float* VEC1 = RN + (size_t)B_ * NUM * HEADS;
  float* VEC2 = VEC1 + NUM;
  float* candV = VEC2 + NUM;
  const size_t NCAND = (size_t)B_ * HEADS * 16 * NJC * 64 * 4;
  int* candI = (int*)(candV + NCAND);
  u64* PK = (u64*)(candI + NCAND);
  bf* XBF = (bf*)(PK + (size_t)B_ * NUM * 16);  // bf16 copy of stage input
  bf* WSC = XBF + SEG;                          // masked relu scores [b][h][i][j] bf16

  float* X1 = nfreg;  // conv1 output (F1 seeded = X1*(1+0.25*[sm==0]))
  float* X2 = out0;   // conv2 output lives in out0 region until final_kernel
  float* Yb = nfreg;  // o2m seed accumulator (= 0.25*[sm==0]*X2, overwrites dead X1)

  // fused: conv1+xbf (y<4) + gts (y 4..7) + pack/vec-zero (y 8..23)
  head_kernel<<<dim3(64, 24), 256, 0, stream>>>(
      input, w1, b1, smask, X1, F1, RN, XBF,
      gt_feat, gt_w, gt_b, gts, mroi, PK, VEC1, VEC2);

  // stage 1: scores once -> scratch + candidates; merge -> vec; PV apply
  score_topk_kernel<<<dim3(16 * NJC, HEADS, B_), 256, 0, stream>>>(
      XBF, RN, PK, WSC, candV, candI);
  topk_merge_kernel<<<64, 256, 0, stream>>>(candV, candI, VEC1);
  pv_kernel<<<dim3(16, HEADS, B_), 256, 0, stream>>>(WSC, X1, RN, VEC1, F1);

  // stage 2 (conv2 also refreshes XBF with bf16(out1) and RN)
  conv_kernel<<<dim3(64, 4), 256, 0, stream>>>(F1, w2, b2, smask, 0.0f, X2, Yb, RN, XBF);
  score_topk_kernel<<<dim3(16 * NJC, HEADS, B_), 256, 0, stream>>>(
      XBF, RN, PK, WSC, candV, candI);
  topk_merge_kernel<<<64, 256, 0, stream>>>(candV, candI, VEC2);
  pv_kernel<<<dim3(16, HEADS, B_), 256, 0, stream>>>(WSC, X2, RN, VEC2, Yb);

  final_kernel<<<4096, 256, 0, stream>>>(Yb, X2, lnw, lnb);
}

// Round 3
// 262.077 us; speedup vs baseline: 1.1702x; 1.1702x over previous
//
#include <hip/hip_runtime.h>
#include <hip/hip_bf16.h>

#define B_    4
#define NUM   1024
#define CH    256
#define HEADS 4
#define DK    64
#define LDK   72   // padded LDS row stride in bf16 elements (2-way bank alias = free)
#define NJC   4    // j-chunks per (b,h,i-tile) in score kernel; chunk = 256 cols

typedef __hip_bfloat16 bf;
typedef __attribute__((ext_vector_type(8))) short short8;
typedef __attribute__((ext_vector_type(4))) float f32x4;
typedef unsigned long long u64;

#define SEG_ ((size_t)B_ * NUM * CH)   // 1048576 elements

__device__ inline bf tobf(float v) { return __float2bfloat16(v); }

// stage a 64x64 fp32 global tile -> bf16 LDS tile (convert path, gts only)
__device__ inline void stage_tile(const float* __restrict__ src, size_t row0,
                                  int col0, int rowstride, bf (*dst)[LDK], int tid) {
  int r = tid >> 4, c4 = (tid & 15) * 4;
  #pragma unroll
  for (int it = 0; it < 4; ++it) {
    int row = r + it * 16;
    const float4 v = *(const float4*)&src[(row0 + row) * (size_t)rowstride + col0 + c4];
    union { bf h4[4]; short4 s4; } u;
    u.h4[0] = tobf(v.x); u.h4[1] = tobf(v.y); u.h4[2] = tobf(v.z); u.h4[3] = tobf(v.w);
    *(short4*)&dst[row][c4] = u.s4;
  }
}

// load this lane's A-fragments straight from the bf16 copy (two 16B loads)
__device__ inline void load_afrag_bf(const bf* __restrict__ arow, int quad, short8 af[2]) {
  af[0] = *(const short8*)&arow[quad * 8];
  af[1] = *(const short8*)&arow[32 + quad * 8];
}

// ---------------- conv body: grouped 1x1 conv + relu, dual write + rn + bf16 x-copy ----------------
__device__ inline void conv_body(
    char* SM, int m0, int g, int tid,
    const float* __restrict__ x, const float* __restrict__ w,
    const float* __restrict__ bias, const int* __restrict__ smask,
    float seedbase, float* __restrict__ out, float* __restrict__ out2,
    float* __restrict__ rn, bf* __restrict__ xbf) {
  float (*Xs)[65] = (float(*)[65])SM;
  float (*Wsm)[65] = (float(*)[65])(SM + 16640);
  const int tx = tid & 15, ty = tid >> 4;
  #pragma unroll
  for (int l = 0; l < 16; ++l) {
    int idx = tid + l * 256; int r = idx >> 6, c = idx & 63;
    Xs[r][c] = x[(size_t)(m0 + r) * CH + g * DK + c];
    Wsm[r][c] = w[g * DK * DK + r * DK + c];
  }
  __syncthreads();
  {  // bf16 copy of the input slice (node-major) for score staging
    int r = tid >> 4, c4 = (tid & 15) * 4;
    #pragma unroll
    for (int it = 0; it < 4; ++it) {
      int row = r + it * 16;
      union { bf h4[4]; short4 s4; } u;
      u.h4[0] = tobf(Xs[row][c4]);     u.h4[1] = tobf(Xs[row][c4 + 1]);
      u.h4[2] = tobf(Xs[row][c4 + 2]); u.h4[3] = tobf(Xs[row][c4 + 3]);
      *(short4*)&xbf[(size_t)(m0 + row) * CH + g * DK + c4] = u.s4;
    }
  }
  {  // fused reciprocal norms: 4 lanes per row, 16 channels each
    int wv = tid >> 6, lane = tid & 63;
    int row = wv * 16 + (lane >> 2), part = lane & 3;
    float s = 0.f;
    #pragma unroll
    for (int k = 0; k < 16; ++k) {
      float v = Xs[row][part * 16 + k];
      s += v * v;
    }
    s += __shfl_xor(s, 1, 64);
    s += __shfl_xor(s, 2, 64);
    if (part == 0)
      rn[(size_t)(m0 + row) * HEADS + g] = 1.0f / fmaxf(sqrtf(s), 1e-4f);
  }
  float acc[4][4] = {};
  #pragma unroll 8
  for (int k = 0; k < DK; ++k) {
    float av[4], bv[4];
    #pragma unroll
    for (int i = 0; i < 4; ++i) av[i] = Xs[ty * 4 + i][k];
    #pragma unroll
    for (int j = 0; j < 4; ++j) bv[j] = Wsm[tx * 4 + j][k];
    #pragma unroll
    for (int i = 0; i < 4; ++i)
      #pragma unroll
      for (int j = 0; j < 4; ++j) acc[i][j] += av[i] * bv[j];
  }
  #pragma unroll
  for (int i = 0; i < 4; ++i) {
    int row = m0 + ty * 4 + i;
    float seed = seedbase + ((smask[row] == 0) ? 0.25f : 0.f);
    #pragma unroll
    for (int j = 0; j < 4; ++j) {
      int o = g * DK + tx * 4 + j;
      size_t idx = (size_t)row * CH + o;
      float v = fmaxf(acc[i][j] + bias[o], 0.f);
      out[idx] = v;
      out2[idx] = v * seed;
    }
  }
}

// ---------------- gts body: relu(gt_feat @ gt_w^T + gt_b), bf16 MFMA ----------------
__device__ inline void gts_body(
    char* SM, int m0, int n0, int tid,
    const float* __restrict__ gf, const float* __restrict__ gw,
    const float* __restrict__ gb, float* __restrict__ out) {
  bf (*As)[LDK] = (bf(*)[LDK])SM;
  bf (*Bs)[LDK] = (bf(*)[LDK])(SM + 9216);
  const int lane = tid & 63, w = tid >> 6;
  const int m = lane & 15, quad = lane >> 4;
  f32x4 acc[4] = {{0.f,0.f,0.f,0.f},{0.f,0.f,0.f,0.f},{0.f,0.f,0.f,0.f},{0.f,0.f,0.f,0.f}};
  for (int k0 = 0; k0 < 256; k0 += 64) {
    __syncthreads();
    stage_tile(gf, m0, k0, 256, As, tid);
    stage_tile(gw, n0, k0, 256, Bs, tid);
    __syncthreads();
    #pragma unroll
    for (int kb = 0; kb < 2; ++kb) {
      short8 a = *(const short8*)&As[w * 16 + m][kb * 32 + quad * 8];
      #pragma unroll
      for (int nt = 0; nt < 4; ++nt) {
        short8 bb = *(const short8*)&Bs[nt * 16 + m][kb * 32 + quad * 8];
        acc[nt] = __builtin_amdgcn_mfma_f32_16x16x32_bf16(a, bb, acc[nt], 0, 0, 0);
      }
    }
  }
  #pragma unroll
  for (int nt = 0; nt < 4; ++nt)
    #pragma unroll
    for (int r = 0; r < 4; ++r) {
      int row = m0 + w * 16 + quad * 4 + r, col = n0 + nt * 16 + m;
      out[(size_t)row * 256 + col] = fmaxf(acc[nt][r] + gb[col], 0.f);
    }
}

// ================ mega head kernel: conv1 (y<4) | gts (y 4..7) | pack (y 8..23) ================
__global__ __launch_bounds__(256) void head_kernel(
    const float* __restrict__ x, const float* __restrict__ w1,
    const float* __restrict__ b1, const int* __restrict__ smask,
    float* __restrict__ X1, float* __restrict__ F1, float* __restrict__ rn,
    bf* __restrict__ xbf,
    const float* __restrict__ gf, const float* __restrict__ gw,
    const float* __restrict__ gb, float* __restrict__ gts_out,
    const int* __restrict__ mroi, u64* __restrict__ pk,
    float* __restrict__ v1, float* __restrict__ v2) {
  __shared__ __align__(16) char SM[33280];
  const int tid = threadIdx.x;
  if (blockIdx.y < 4) {
    conv_body(SM, blockIdx.x * 64, blockIdx.y, tid, x, w1, b1, smask, 1.0f, X1, F1, rn, xbf);
  } else if (blockIdx.y < 8) {
    gts_body(SM, blockIdx.x * 64, (blockIdx.y - 4) * 64, tid, gf, gw, gb, gts_out);
  } else {
    int blkrow = (blockIdx.y - 8) * 64 + blockIdx.x;   // 0..1023
    if (blkrow < 4) {
      int i = blkrow * 256 + tid;
      v1[i] = 0.f; v2[i] = 0.f;
    }
    int row = blkrow * 4 + (tid >> 6);
    int lane = tid & 63;
    int b = row >> 10;
    const int* mr = &mroi[(size_t)row * NUM];
    const int* sm = &smask[b * NUM];
    #pragma unroll
    for (int wd = 0; wd < 16; ++wd) {
      int j = wd * 64 + lane;
      u64 word = __ballot((mr[j] != 0) && (sm[j] != 0));
      if (lane == 0) pk[(size_t)row * 16 + wd] = word;
    }
  }
}

// ---------------- grouped 1x1 conv + relu (fp32) standalone (stage 2) ----------------
__global__ __launch_bounds__(256) void conv_kernel(
    const float* __restrict__ x, const float* __restrict__ w,
    const float* __restrict__ bias, const int* __restrict__ smask,
    float seedbase, float* __restrict__ out, float* __restrict__ out2,
    float* __restrict__ rn, bf* __restrict__ xbf) {
  __shared__ __align__(16) char SM[33280];
  conv_body(SM, blockIdx.x * 64, blockIdx.y, threadIdx.x, x, w, bias, smask,
            seedbase, out, out2, rn, xbf);
}

// top-4 insert, jax-stable tie-break (higher value first; equal value -> lower index)
__device__ inline void ins4(float v, int id, float tv[4], int tj[4]) {
  if (v < tv[3] || (v == tv[3] && id > tj[3])) return;
  tv[3] = v; tj[3] = id;
  #pragma unroll
  for (int k = 3; k > 0; --k) {
    bool sw = (tv[k] > tv[k - 1]) || (tv[k] == tv[k - 1] && tj[k] < tj[k - 1]);
    if (sw) {
      float fv = tv[k]; tv[k] = tv[k - 1]; tv[k - 1] = fv;
      int ti = tj[k]; tj[k] = tj[k - 1]; tj[k - 1] = ti;
    }
  }
}

// ---------------- fused scores + top-4 (scores computed ONCE per stage) ----------------
// LDS-staged Xj tiles (double-buffered, issue-early/write-late), MFMA scores,
// pk-masked relu scores (bf16) -> WS scratch for the pv kernel, per-row top-4
// candidates via in-register shfl_xor butterfly merge across the 16 m-lanes.
// Ranking on relu(dot*rnj): identical order & zero-ties to relu(dot/(ni*nj)).
__global__ __launch_bounds__(256) void score_topk_kernel(
    const bf* __restrict__ xbf, const float* __restrict__ rn,
    const u64* __restrict__ pk, bf* __restrict__ wsout,
    float* __restrict__ candV, int* __restrict__ candI) {
  __shared__ __align__(16) bf Xj[2][64][LDK];
  const int b = blockIdx.z, h = blockIdx.y;
  const int it = blockIdx.x >> 2, jc = blockIdx.x & 3;
  const int i0 = it * 64;
  const int tid = threadIdx.x, lane = tid & 63, w = tid >> 6;
  const int m = lane & 15, quad = lane >> 4;
  const int srow = tid >> 3, schunk = tid & 7;   // staging decomposition

  short8 afrag[2];
  load_afrag_bf(&xbf[((size_t)b * NUM + i0 + w * 16 + m) * CH + h * DK], quad, afrag);

  float tv[4][4]; int tj[4][4];
  #pragma unroll
  for (int r = 0; r < 4; ++r)
    #pragma unroll
    for (int q = 0; q < 4; ++q) { tv[r][q] = -1.f; tj[r][q] = 0xffff; }

  const size_t wsrow0 = (size_t)(b * HEADS + h) * NUM + i0 + w * 16 + quad * 4;

  // staging lambdas: global loads to regs (issue-early), regs -> LDS (write-late)
  auto sload = [&](int jt, short8& n0, short8& n1) {
    size_t base = (size_t)b * NUM + jc * 256 + jt * 64;
    n0 = *(const short8*)&xbf[(base + srow) * CH + h * DK + schunk * 8];
    n1 = *(const short8*)&xbf[(base + srow + 32) * CH + h * DK + schunk * 8];
  };
  auto swrite = [&](int buf, short8 n0, short8 n1) {
    *(short8*)&Xj[buf][srow][schunk * 8] = n0;
    *(short8*)&Xj[buf][srow + 32][schunk * 8] = n1;
  };

  {  // prologue: stage tile 0
    short8 n0, n1;
    sload(0, n0, n1);
    swrite(0, n0, n1);
  }
  __syncthreads();

  #pragma unroll
  for (int jt = 0; jt < 4; ++jt) {
    const int cur = jt & 1;
    const int j0 = jc * 256 + jt * 64;
    short8 n0, n1;
    if (jt < 3) sload(jt + 1, n0, n1);   // next tile's globals in flight over MFMA phase
    u64 wr[4];
    float rnj4[4];
    #pragma unroll
    for (int r = 0; r < 4; ++r)
      wr[r] = pk[((size_t)b * NUM + i0 + w * 16 + quad * 4 + r) * 16 + (j0 >> 6)];
    #pragma unroll
    for (int nt = 0; nt < 4; ++nt)
      rnj4[nt] = rn[((size_t)b * NUM + j0 + nt * 16 + m) * HEADS + h];
    #pragma unroll
    for (int nt = 0; nt < 4; ++nt) {
      f32x4 acc = {0.f, 0.f, 0.f, 0.f};
      #pragma unroll
      for (int kb = 0; kb < 2; ++kb) {
        short8 bb = *(const short8*)&Xj[cur][nt * 16 + m][kb * 32 + quad * 8];
        acc = __builtin_amdgcn_mfma_f32_16x16x32_bf16(afrag[kb], bb, acc, 0, 0, 0);
      }
      const int j = j0 + nt * 16 + m;
      #pragma unroll
      for (int r = 0; r < 4; ++r) {
        float rel = fmaxf(acc[r], 0.f);
        ins4(rel * rnj4[nt], j, tv[r], tj[r]);
        bool bit = (wr[r] >> (nt * 16 + m)) & 1ull;
        wsout[(wsrow0 + r) * NUM + j] = tobf(bit ? rel : 0.f);
      }
    }
    if (jt < 3) swrite(cur ^ 1, n0, n1);
    __syncthreads();
  }

  // butterfly merge of top-4 lists across the 16 m-lanes of each quad group
  #pragma unroll
  for (int st = 1; st < 16; st <<= 1) {
    #pragma unroll
    for (int r = 0; r < 4; ++r) {
      float ov[4]; int oj[4];
      #pragma unroll
      for (int q = 0; q < 4; ++q) {
        ov[q] = __shfl_xor(tv[r][q], st, 64);
        oj[q] = __shfl_xor(tj[r][q], st, 64);
      }
      #pragma unroll
      for (int q = 0; q < 4; ++q) ins4(ov[q], oj[q], tv[r], tj[r]);
    }
  }
  if (m == 0) {
    #pragma unroll
    for (int r = 0; r < 4; ++r) {
      int rl = w * 16 + quad * 4 + r;
      size_t base = (size_t)((((b * HEADS + h) * 16 + it) * NJC + jc) * 64 + rl) * 4;
      #pragma unroll
      for (int q = 0; q < 4; ++q) { candV[base + q] = tv[r][q]; candI[base + q] = tj[r][q]; }
    }
  }
}

// ---------------- merge NJC chunk candidates per row -> union into vec ----------------
__global__ __launch_bounds__(256) void topk_merge_kernel(
    const float* __restrict__ candV, const int* __restrict__ candI,
    float* __restrict__ vec) {
  int t = blockIdx.x * 256 + threadIdx.x;   // t = bhit*64 + rl
  int bhit = t >> 6, rl = t & 63;
  float fv[4] = {-1.f, -1.f, -1.f, -1.f};
  int fi[4] = {0x7fffffff, 0x7fffffff, 0x7fffffff, 0x7fffffff};
  #pragma unroll
  for (int jc = 0; jc < NJC; ++jc) {
    size_t base = (size_t)(((bhit) * NJC + jc) * 64 + rl) * 4;
    #pragma unroll
    for (int q = 0; q < 4; ++q) ins4(candV[base + q], candI[base + q], fv, fi);
  }
  #pragma unroll
  for (int q = 0; q < 4; ++q) vec[fi[q]] = 1.0f;  // benign race, all write 1
}

// ---------------- PV apply: om = Ws(scratch) @ Cv, exclusive tiles, no atomics ----------------
// Block (it,h,b) owns i-rows [i0,i0+64) x channels [h*DK, h*DK+64): writes are exclusive.
// A-frags stream straight from the WS scratch (prefetched 1 tile ahead in regs);
// Cv (conv^T scaled by vec*rnj, bf16) is issue-early/write-late double-buffered in LDS.
__global__ __launch_bounds__(256) void pv_kernel(
    const bf* __restrict__ wsin, const float* __restrict__ conv,
    const float* __restrict__ rn, const float* __restrict__ vec,
    float* __restrict__ out) {
  __shared__ __align__(16) bf Cv[2][64][LDK];
  const int b = blockIdx.z, h = blockIdx.y, it = blockIdx.x;
  const int i0 = it * 64;
  const int tid = threadIdx.x, lane = tid & 63, w = tid >> 6;
  const int m = lane & 15, quad = lane >> 4;
  const int jr = tid >> 4, c4 = tid & 15;

  float rni4[4];
  #pragma unroll
  for (int r = 0; r < 4; ++r)
    rni4[r] = 0.25f * rn[((size_t)b * NUM + i0 + w * 16 + quad * 4 + r) * HEADS + h];

  const size_t wsrow = ((size_t)(b * HEADS + h) * NUM + i0 + w * 16 + m) * NUM;

  f32x4 om[4] = {{0.f,0.f,0.f,0.f},{0.f,0.f,0.f,0.f},{0.f,0.f,0.f,0.f},{0.f,0.f,0.f,0.f}};

  float4 pre[4]; float psc[4];
  // --- issue global loads of Cv tile jt ---
  auto issue = [&](int jt) {
    #pragma unroll
    for (int itt = 0; itt < 4; ++itt) {
      int j = jt * 64 + jr + itt * 16;
      psc[itt] = vec[j] * rn[((size_t)b * NUM + j) * HEADS + h];
      pre[itt] = *(const float4*)&conv[((size_t)b * NUM + j) * CH + h * DK + c4 * 4];
    }
  };
  // --- convert + write staged regs into LDS buffer ---
  auto lwrite = [&](int buf) {
    #pragma unroll
    for (int itt = 0; itt < 4; ++itt) {
      int j = jr + itt * 16;
      Cv[buf][c4 * 4 + 0][j] = tobf(pre[itt].x * psc[itt]);
      Cv[buf][c4 * 4 + 1][j] = tobf(pre[itt].y * psc[itt]);
      Cv[buf][c4 * 4 + 2][j] = tobf(pre[itt].z * psc[itt]);
      Cv[buf][c4 * 4 + 3][j] = tobf(pre[itt].w * psc[itt]);
    }
  };

  issue(0); lwrite(0);
  short8 a0 = *(const short8*)&wsin[wsrow + quad * 8];
  short8 a1 = *(const short8*)&wsin[wsrow + 32 + quad * 8];

  for (int jt = 0; jt < 16; ++jt) {
    const int cur = jt & 1;
    short8 na0, na1;
    if (jt < 15) {
      issue(jt + 1);   // global loads in flight across the MFMA phase
      na0 = *(const short8*)&wsin[wsrow + (jt + 1) * 64 + quad * 8];
      na1 = *(const short8*)&wsin[wsrow + (jt + 1) * 64 + 32 + quad * 8];
    }
    __syncthreads();   // Cv[cur] fully written; prior readers of Cv[cur^1] done
    #pragma unroll
    for (int ct = 0; ct < 4; ++ct)
      om[ct] = __builtin_amdgcn_mfma_f32_16x16x32_bf16(
          a0, *(const short8*)&Cv[cur][ct * 16 + m][quad * 8], om[ct], 0, 0, 0);
    #pragma unroll
    for (int ct = 0; ct < 4; ++ct)
      om[ct] = __builtin_amdgcn_mfma_f32_16x16x32_bf16(
          a1, *(const short8*)&Cv[cur][ct * 16 + m][32 + quad * 8], om[ct], 0, 0, 0);
    if (jt < 15) lwrite(cur ^ 1);
    a0 = na0; a1 = na1;
  }

  #pragma unroll
  for (int ct = 0; ct < 4; ++ct)
    #pragma unroll
    for (int r = 0; r < 4; ++r) {
      size_t idx = ((size_t)b * NUM + i0 + w * 16 + quad * 4 + r) * CH + h * DK + ct * 16 + m;
      out[idx] += om[ct][r] * rni4[r];   // exclusive tile: plain RMW
    }
}

// ---------------- LayerNorm + final outputs (in-place on d_out regions) ----------------
__global__ __launch_bounds__(256) void final_kernel(
    float* __restrict__ ybnf, float* __restrict__ out0,
    const float* __restrict__ lnw, const float* __restrict__ lnb) {
  __shared__ float r1[4];
  __shared__ float r2[4];
  int bn = blockIdx.x;
  int c = threadIdx.x;
  size_t idx = (size_t)bn * CH + c;
  float y = ybnf[idx];
  float x2v = out0[idx];
  float s = y;
  #pragma unroll
  for (int off = 32; off; off >>= 1) s += __shfl_down(s, off, 64);
  int wave = c >> 6, lane = c & 63;
  if (lane == 0) r1[wave] = s;
  __syncthreads();
  float mu = (r1[0] + r1[1] + r1[2] + r1[3]) * (1.f / 256.f);
  float d = y - mu;
  float s2 = d * d;
  #pragma unroll
  for (int off = 32; off; off >>= 1) s2 += __shfl_down(s2, off, 64);
  if (lane == 0) r2[wave] = s2;
  __syncthreads();
  float var = (r2[0] + r2[1] + r2[2] + r2[3]) * (1.f / 256.f);
  float nf = d * rsqrtf(var + 1e-6f) * lnw[c] + lnb[c];
  ybnf[idx] = nf;
  out0[idx] = x2v + nf;
}

extern "C" void kernel_launch(void* const* d_in, const int* in_sizes, int n_in,
                              void* d_out, int out_size, void* d_ws, size_t ws_size,
                              hipStream_t stream) {
  const float* input = (const float*)d_in[0];
  const int* mroi = (const int*)d_in[1];
  const int* smask = (const int*)d_in[2];
  const float* gt_feat = (const float*)d_in[3];
  const float* w1 = (const float*)d_in[4];
  const float* b1 = (const float*)d_in[5];
  const float* w2 = (const float*)d_in[6];
  const float* b2 = (const float*)d_in[7];
  const float* gt_w = (const float*)d_in[8];
  const float* gt_b = (const float*)d_in[9];
  const float* lnw = (const float*)d_in[10];
  const float* lnb = (const float*)d_in[11];

  const size_t SEG = SEG_;         // 1048576 elements
  float* out0 = (float*)d_out;     // finally: out2^T + node_feat ; interim: X2 (conv2)
  float* gts = out0 + SEG;         // gts output (final from the start)
  float* nfreg = out0 + 2 * SEG;   // finally: node_feat ; interim: X1 then Yb

  // ws: F1 4MB | RN 64KB | VEC 8KB | candV 4MB | candI 4MB | PK 512KB | XBF 2MB | WS 32MB
  float* F1 = (float*)d_ws;
  float* RN = F1 + SEG;
  float* VEC1 = RN + (size_t)B_ * NUM * HEADS;
  float* VEC2 = VEC1 + NUM;
  float* candV = VEC2 + NUM;
  const size_t NCAND = (size_t)B_ * HEADS * 16 * NJC * 64 * 4;
  int* candI = (int*)(candV + NCAND);
  u64* PK = (u64*)(candI + NCAND);
  bf* XBF = (bf*)(PK + (size_t)B_ * NUM * 16);  // bf16 copy of stage input
  bf* WSC = XBF + SEG;                          // masked relu scores [b][h][i][j] bf16

  float* X1 = nfreg;  // conv1 output (F1 seeded = X1*(1+0.25*[sm==0]))
  float* X2 = out0;   // conv2 output lives in out0 region until final_kernel
  float* Yb = nfreg;  // o2m seed accumulator (= 0.25*[sm==0]*X2, overwrites dead X1)

  // fused: conv1+xbf (y<4) + gts (y 4..7) + pack/vec-zero (y 8..23)
  head_kernel<<<dim3(64, 24), 256, 0, stream>>>(
      input, w1, b1, smask, X1, F1, RN, XBF,
      gt_feat, gt_w, gt_b, gts, mroi, PK, VEC1, VEC2);

  // stage 1: scores once -> scratch + candidates; merge -> vec; PV apply
  score_topk_kernel<<<dim3(16 * NJC, HEADS, B_), 256, 0, stream>>>(
      XBF, RN, PK, WSC, candV, candI);
  topk_merge_kernel<<<64, 256, 0, stream>>>(candV, candI, VEC1);
  pv_kernel<<<dim3(16, HEADS, B_), 256, 0, stream>>>(WSC, X1, RN, VEC1, F1);

  // stage 2 (conv2 also refreshes XBF with bf16(out1) and RN)
  conv_kernel<<<dim3(64, 4), 256, 0, stream>>>(F1, w2, b2, smask, 0.0f, X2, Yb, RN, XBF);
  score_topk_kernel<<<dim3(16 * NJC, HEADS, B_), 256, 0, stream>>>(
      XBF, RN, PK, WSC, candV, candI);
  topk_merge_kernel<<<64, 256, 0, stream>>>(candV, candI, VEC2);
  pv_kernel<<<dim3(16, HEADS, B_), 256, 0, stream>>>(WSC, X2, RN, VEC2, Yb);

  final_kernel<<<4096, 256, 0, stream>>>(Yb, X2, lnw, lnb);
}

// Round 4
// 221.479 us; speedup vs baseline: 1.3847x; 1.1833x over previous
//
#include <hip/hip_runtime.h>
#include <hip/hip_bf16.h>

#define B_    4
#define NUM   1024
#define CH    256
#define HEADS 4
#define DK    64
#define LDK   72   // padded LDS row stride in bf16 elements (2-way bank alias = free)
#define NJC   4    // j-chunks per (b,h,i-tile); chunk = 256 cols = 4 j-tiles

typedef __hip_bfloat16 bf;
typedef __attribute__((ext_vector_type(8))) short short8;
typedef __attribute__((ext_vector_type(4))) float f32x4;
typedef unsigned long long u64;

#define SEG_ ((size_t)B_ * NUM * CH)   // 1048576 elements

__device__ inline bf tobf(float v) { return __float2bfloat16(v); }

// stage a 64x64 fp32 global tile -> bf16 LDS tile (convert path, gts only)
__device__ inline void stage_tile(const float* __restrict__ src, size_t row0,
                                  int col0, int rowstride, bf (*dst)[LDK], int tid) {
  int r = tid >> 4, c4 = (tid & 15) * 4;
  #pragma unroll
  for (int it = 0; it < 4; ++it) {
    int row = r + it * 16;
    const float4 v = *(const float4*)&src[(row0 + row) * (size_t)rowstride + col0 + c4];
    union { bf h4[4]; short4 s4; } u;
    u.h4[0] = tobf(v.x); u.h4[1] = tobf(v.y); u.h4[2] = tobf(v.z); u.h4[3] = tobf(v.w);
    *(short4*)&dst[row][c4] = u.s4;
  }
}

// load this lane's A-fragments straight from the bf16 copy (two 16B loads)
__device__ inline void load_afrag_bf(const bf* __restrict__ arow, int quad, short8 af[2]) {
  af[0] = *(const short8*)&arow[quad * 8];
  af[1] = *(const short8*)&arow[32 + quad * 8];
}

// ---- packed top-4 machinery: key = (f32_bits(v) << 32) | ~j  (v >= 0) ----
// Monotonic in v (non-negative IEEE), ties broken toward LOWER j (higher ~j),
// matching jax top_k stable semantics. Lists kept sorted descending.
__device__ inline u64 shfl_xor64(u64 v, int mask) {
  int lo = __shfl_xor((int)(unsigned)(v & 0xFFFFFFFFull), mask, 64);
  int hi = __shfl_xor((int)(unsigned)(v >> 32), mask, 64);
  return ((u64)(unsigned)hi << 32) | (unsigned)lo;
}

// streaming insert of one key into a sorted-desc top-4 list (branchless)
__device__ inline void ins4k(u64 k, u64 t[4]) {
  u64 x;
  t[3] = k > t[3] ? k : t[3];
  if (t[3] > t[2]) { x = t[2]; t[2] = t[3]; t[3] = x; }
  if (t[2] > t[1]) { x = t[1]; t[1] = t[2]; t[2] = x; }
  if (t[1] > t[0]) { x = t[0]; t[0] = t[1]; t[1] = x; }
}

// merge another sorted-desc 4-list into ours: bitonic half-cleaner + 4-sort
__device__ inline void merge4(u64 t[4], u64 o0, u64 o1, u64 o2, u64 o3) {
  u64 m0 = t[0] > o3 ? t[0] : o3;
  u64 m1 = t[1] > o2 ? t[1] : o2;
  u64 m2 = t[2] > o1 ? t[2] : o1;
  u64 m3 = t[3] > o0 ? t[3] : o0;
  u64 x;
  if (m0 < m2) { x = m0; m0 = m2; m2 = x; }
  if (m1 < m3) { x = m1; m1 = m3; m3 = x; }
  if (m0 < m1) { x = m0; m0 = m1; m1 = x; }
  if (m2 < m3) { x = m2; m2 = m3; m3 = x; }
  t[0] = m0; t[1] = m1; t[2] = m2; t[3] = m3;
}

// ---------------- conv body: grouped 1x1 conv + relu, dual write + rn + bf16 x-copy ----------------
// parts != nullptr: input is x + parts[0..3] (pv partials folded at load time)
__device__ inline void conv_body(
    char* SM, int m0, int g, int tid,
    const float* __restrict__ x, const float* __restrict__ parts,
    const float* __restrict__ w,
    const float* __restrict__ bias, const int* __restrict__ smask,
    float seedbase, float* __restrict__ out, float* __restrict__ out2,
    float* __restrict__ rn, bf* __restrict__ xbf) {
  float (*Xs)[65] = (float(*)[65])SM;
  float (*Wsm)[65] = (float(*)[65])(SM + 16640);
  const int tx = tid & 15, ty = tid >> 4;
  #pragma unroll
  for (int l = 0; l < 16; ++l) {
    int idx = tid + l * 256; int r = idx >> 6, c = idx & 63;
    size_t gi = (size_t)(m0 + r) * CH + g * DK + c;
    float v = x[gi];
    if (parts)
      v += parts[gi] + parts[SEG_ + gi] + parts[2 * SEG_ + gi] + parts[3 * SEG_ + gi];
    Xs[r][c] = v;
    Wsm[r][c] = w[g * DK * DK + r * DK + c];
  }
  __syncthreads();
  {  // bf16 copy of the input slice (node-major) for score staging
    int r = tid >> 4, c4 = (tid & 15) * 4;
    #pragma unroll
    for (int it = 0; it < 4; ++it) {
      int row = r + it * 16;
      union { bf h4[4]; short4 s4; } u;
      u.h4[0] = tobf(Xs[row][c4]);     u.h4[1] = tobf(Xs[row][c4 + 1]);
      u.h4[2] = tobf(Xs[row][c4 + 2]); u.h4[3] = tobf(Xs[row][c4 + 3]);
      *(short4*)&xbf[(size_t)(m0 + row) * CH + g * DK + c4] = u.s4;
    }
  }
  {  // fused reciprocal norms: 4 lanes per row, 16 channels each
    int wv = tid >> 6, lane = tid & 63;
    int row = wv * 16 + (lane >> 2), part = lane & 3;
    float s = 0.f;
    #pragma unroll
    for (int k = 0; k < 16; ++k) {
      float v = Xs[row][part * 16 + k];
      s += v * v;
    }
    s += __shfl_xor(s, 1, 64);
    s += __shfl_xor(s, 2, 64);
    if (part == 0)
      rn[(size_t)(m0 + row) * HEADS + g] = 1.0f / fmaxf(sqrtf(s), 1e-4f);
  }
  float acc[4][4] = {};
  #pragma unroll 8
  for (int k = 0; k < DK; ++k) {
    float av[4], bv[4];
    #pragma unroll
    for (int i = 0; i < 4; ++i) av[i] = Xs[ty * 4 + i][k];
    #pragma unroll
    for (int j = 0; j < 4; ++j) bv[j] = Wsm[tx * 4 + j][k];
    #pragma unroll
    for (int i = 0; i < 4; ++i)
      #pragma unroll
      for (int j = 0; j < 4; ++j) acc[i][j] += av[i] * bv[j];
  }
  #pragma unroll
  for (int i = 0; i < 4; ++i) {
    int row = m0 + ty * 4 + i;
    float seed = seedbase + ((smask[row] == 0) ? 0.25f : 0.f);
    #pragma unroll
    for (int j = 0; j < 4; ++j) {
      int o = g * DK + tx * 4 + j;
      size_t idx = (size_t)row * CH + o;
      float v = fmaxf(acc[i][j] + bias[o], 0.f);
      out[idx] = v;
      out2[idx] = v * seed;
    }
  }
}

// ---------------- gts body: relu(gt_feat @ gt_w^T + gt_b), bf16 MFMA ----------------
__device__ inline void gts_body(
    char* SM, int m0, int n0, int tid,
    const float* __restrict__ gf, const float* __restrict__ gw,
    const float* __restrict__ gb, float* __restrict__ out) {
  bf (*As)[LDK] = (bf(*)[LDK])SM;
  bf (*Bs)[LDK] = (bf(*)[LDK])(SM + 9216);
  const int lane = tid & 63, w = tid >> 6;
  const int m = lane & 15, quad = lane >> 4;
  f32x4 acc[4] = {{0.f,0.f,0.f,0.f},{0.f,0.f,0.f,0.f},{0.f,0.f,0.f,0.f},{0.f,0.f,0.f,0.f}};
  for (int k0 = 0; k0 < 256; k0 += 64) {
    __syncthreads();
    stage_tile(gf, m0, k0, 256, As, tid);
    stage_tile(gw, n0, k0, 256, Bs, tid);
    __syncthreads();
    #pragma unroll
    for (int kb = 0; kb < 2; ++kb) {
      short8 a = *(const short8*)&As[w * 16 + m][kb * 32 + quad * 8];
      #pragma unroll
      for (int nt = 0; nt < 4; ++nt) {
        short8 bb = *(const short8*)&Bs[nt * 16 + m][kb * 32 + quad * 8];
        acc[nt] = __builtin_amdgcn_mfma_f32_16x16x32_bf16(a, bb, acc[nt], 0, 0, 0);
      }
    }
  }
  #pragma unroll
  for (int nt = 0; nt < 4; ++nt)
    #pragma unroll
    for (int r = 0; r < 4; ++r) {
      int row = m0 + w * 16 + quad * 4 + r, col = n0 + nt * 16 + m;
      out[(size_t)row * 256 + col] = fmaxf(acc[nt][r] + gb[col], 0.f);
    }
}

// ================ mega head kernel: conv1 (y<4) | gts (y 4..7) | pack (y 8..23) ================
__global__ __launch_bounds__(256) void head_kernel(
    const float* __restrict__ x, const float* __restrict__ w1,
    const float* __restrict__ b1, const int* __restrict__ smask,
    float* __restrict__ X1, float* __restrict__ F1, float* __restrict__ rn,
    bf* __restrict__ xbf,
    const float* __restrict__ gf, const float* __restrict__ gw,
    const float* __restrict__ gb, float* __restrict__ gts_out,
    const int* __restrict__ mroi, u64* __restrict__ pk,
    float* __restrict__ v1, float* __restrict__ v2) {
  __shared__ __align__(16) char SM[33280];
  const int tid = threadIdx.x;
  if (blockIdx.y < 4) {
    conv_body(SM, blockIdx.x * 64, blockIdx.y, tid, x, nullptr, w1, b1, smask,
              1.0f, X1, F1, rn, xbf);
  } else if (blockIdx.y < 8) {
    gts_body(SM, blockIdx.x * 64, (blockIdx.y - 4) * 64, tid, gf, gw, gb, gts_out);
  } else {
    int blkrow = (blockIdx.y - 8) * 64 + blockIdx.x;   // 0..1023
    if (blkrow < 4) {
      int i = blkrow * 256 + tid;
      v1[i] = 0.f; v2[i] = 0.f;
    }
    int row = blkrow * 4 + (tid >> 6);
    int lane = tid & 63;
    int b = row >> 10;
    const int* mr = &mroi[(size_t)row * NUM];
    const int* sm = &smask[b * NUM];
    #pragma unroll
    for (int wd = 0; wd < 16; ++wd) {
      int j = wd * 64 + lane;
      u64 word = __ballot((mr[j] != 0) && (sm[j] != 0));
      if (lane == 0) pk[(size_t)row * 16 + wd] = word;
    }
  }
}

// ---------------- grouped 1x1 conv + relu (fp32) standalone (stage 2) ----------------
__global__ __launch_bounds__(256) void conv_kernel(
    const float* __restrict__ x, const float* __restrict__ parts,
    const float* __restrict__ w,
    const float* __restrict__ bias, const int* __restrict__ smask,
    float seedbase, float* __restrict__ out, float* __restrict__ out2,
    float* __restrict__ rn, bf* __restrict__ xbf) {
  __shared__ __align__(16) char SM[33280];
  conv_body(SM, blockIdx.x * 64, blockIdx.y, threadIdx.x, x, parts, w, bias, smask,
            seedbase, out, out2, rn, xbf);
}

// ---------------- fused scores + top-4 (scores computed ONCE per stage) ----------------
// LDS-staged Xj tiles (double-buffered, issue-early/write-late), MFMA scores,
// pk-masked relu scores (bf16) -> WS scratch for the pv kernel, per-row top-4 as
// packed u64 keys merged across the 16 m-lanes via shfl_xor + bitonic half-cleaner.
__global__ __launch_bounds__(256) void score_topk_kernel(
    const bf* __restrict__ xbf, const float* __restrict__ rn,
    const u64* __restrict__ pk, bf* __restrict__ wsout,
    u64* __restrict__ candK) {
  __shared__ __align__(16) bf Xj[2][64][LDK];
  const int b = blockIdx.z, h = blockIdx.y;
  const int it = blockIdx.x >> 2, jc = blockIdx.x & 3;
  const int i0 = it * 64;
  const int tid = threadIdx.x, lane = tid & 63, w = tid >> 6;
  const int m = lane & 15, quad = lane >> 4;
  const int srow = tid >> 3, schunk = tid & 7;   // staging decomposition

  short8 afrag[2];
  load_afrag_bf(&xbf[((size_t)b * NUM + i0 + w * 16 + m) * CH + h * DK], quad, afrag);

  u64 keys[4][4] = {};   // sorted-desc top-4 packed keys, one list per row r

  // hoisted wsout row pointers
  bf* wsp[4];
  #pragma unroll
  for (int r = 0; r < 4; ++r)
    wsp[r] = wsout + ((size_t)(b * HEADS + h) * NUM + i0 + w * 16 + quad * 4 + r) * NUM;

  // staging lambdas: global loads to regs (issue-early), regs -> LDS (write-late)
  auto sload = [&](int jt, short8& n0, short8& n1) {
    size_t base = (size_t)b * NUM + jc * 256 + jt * 64;
    n0 = *(const short8*)&xbf[(base + srow) * CH + h * DK + schunk * 8];
    n1 = *(const short8*)&xbf[(base + srow + 32) * CH + h * DK + schunk * 8];
  };
  auto swrite = [&](int buf, short8 n0, short8 n1) {
    *(short8*)&Xj[buf][srow][schunk * 8] = n0;
    *(short8*)&Xj[buf][srow + 32][schunk * 8] = n1;
  };

  {  // prologue: stage tile 0
    short8 n0, n1;
    sload(0, n0, n1);
    swrite(0, n0, n1);
  }
  __syncthreads();

  #pragma unroll
  for (int jt = 0; jt < 4; ++jt) {
    const int cur = jt & 1;
    const int j0 = jc * 256 + jt * 64;
    short8 n0, n1;
    if (jt < 3) sload(jt + 1, n0, n1);   // next tile's globals in flight over MFMA phase
    u64 wr[4];
    float rnj4[4];
    #pragma unroll
    for (int r = 0; r < 4; ++r)
      wr[r] = pk[((size_t)b * NUM + i0 + w * 16 + quad * 4 + r) * 16 + (j0 >> 6)];
    #pragma unroll
    for (int nt = 0; nt < 4; ++nt)
      rnj4[nt] = rn[((size_t)b * NUM + j0 + nt * 16 + m) * HEADS + h];
    #pragma unroll
    for (int nt = 0; nt < 4; ++nt) {
      f32x4 acc = {0.f, 0.f, 0.f, 0.f};
      #pragma unroll
      for (int kb = 0; kb < 2; ++kb) {
        short8 bb = *(const short8*)&Xj[cur][nt * 16 + m][kb * 32 + quad * 8];
        acc = __builtin_amdgcn_mfma_f32_16x16x32_bf16(afrag[kb], bb, acc, 0, 0, 0);
      }
      const int j = j0 + nt * 16 + m;
      const unsigned jinv = ~(unsigned)j;
      const int bsh = nt * 16 + m;
      #pragma unroll
      for (int r = 0; r < 4; ++r) {
        float rel = fmaxf(acc[r], 0.f);
        u64 k = ((u64)__float_as_uint(rel * rnj4[nt]) << 32) | jinv;
        ins4k(k, keys[r]);
        bool bit = (wr[r] >> bsh) & 1ull;
        wsp[r][j] = tobf(bit ? rel : 0.f);
      }
    }
    if (jt < 3) swrite(cur ^ 1, n0, n1);
    __syncthreads();
  }

  // butterfly merge across the 16 m-lanes of each quad group
  #pragma unroll
  for (int st = 1; st < 16; st <<= 1) {
    #pragma unroll
    for (int r = 0; r < 4; ++r) {
      u64 o0 = shfl_xor64(keys[r][0], st);
      u64 o1 = shfl_xor64(keys[r][1], st);
      u64 o2 = shfl_xor64(keys[r][2], st);
      u64 o3 = shfl_xor64(keys[r][3], st);
      merge4(keys[r], o0, o1, o2, o3);
    }
  }
  if (m == 0) {
    #pragma unroll
    for (int r = 0; r < 4; ++r) {
      int rl = w * 16 + quad * 4 + r;
      u64* dst = &candK[(size_t)((((b * HEADS + h) * 16 + it) * NJC + jc) * 64 + rl) * 4];
      #pragma unroll
      for (int q = 0; q < 4; ++q) dst[q] = keys[r][q];
    }
  }
}

// ---------------- merge NJC chunk candidates per row -> union into vec ----------------
__global__ __launch_bounds__(256) void topk_merge_kernel(
    const u64* __restrict__ candK, float* __restrict__ vec) {
  int t = blockIdx.x * 256 + threadIdx.x;   // t = bhit*64 + rl
  int bhit = t >> 6, rl = t & 63;
  u64 best[4] = {};
  #pragma unroll
  for (int jc = 0; jc < NJC; ++jc) {
    const u64* c = &candK[(size_t)((bhit * NJC + jc) * 64 + rl) * 4];
    merge4(best, c[0], c[1], c[2], c[3]);
  }
  #pragma unroll
  for (int q = 0; q < 4; ++q) vec[~(unsigned)best[q]] = 1.0f;  // benign race, all write 1
}

// ---------------- PV apply: om = Ws(scratch) @ Cv, j-chunked partials ----------------
// Block (it,jc,h,b) owns i-rows [i0,i0+64) x channels [h*DK,+64) over j-chunk jc.
// Plain stores into partial slice P[jc] (consumers fold the 4-way sum).
// A-frags stream from WS scratch (prefetched 1 tile ahead in regs); Cv
// (conv^T scaled by vec*rnj, bf16) is issue-early/write-late double-buffered in LDS.
__global__ __launch_bounds__(256) void pv_kernel(
    const bf* __restrict__ wsin, const float* __restrict__ conv,
    const float* __restrict__ rn, const float* __restrict__ vec,
    float* __restrict__ outp) {
  __shared__ __align__(16) bf Cv[2][64][LDK];
  const int b = blockIdx.z, h = blockIdx.y;
  const int it = blockIdx.x >> 2, jc = blockIdx.x & 3;
  const int i0 = it * 64, jbase = jc * 256;
  const int tid = threadIdx.x, lane = tid & 63, w = tid >> 6;
  const int m = lane & 15, quad = lane >> 4;
  const int jr = tid >> 4, c4 = tid & 15;

  float rni4[4];
  #pragma unroll
  for (int r = 0; r < 4; ++r)
    rni4[r] = 0.25f * rn[((size_t)b * NUM + i0 + w * 16 + quad * 4 + r) * HEADS + h];

  const size_t wsrow = ((size_t)(b * HEADS + h) * NUM + i0 + w * 16 + m) * NUM + jbase;

  f32x4 om[4] = {{0.f,0.f,0.f,0.f},{0.f,0.f,0.f,0.f},{0.f,0.f,0.f,0.f},{0.f,0.f,0.f,0.f}};

  float4 pre[4]; float psc[4];
  // --- issue global loads of Cv tile jt ---
  auto issue = [&](int jt) {
    #pragma unroll
    for (int itt = 0; itt < 4; ++itt) {
      int j = jbase + jt * 64 + jr + itt * 16;
      psc[itt] = vec[j] * rn[((size_t)b * NUM + j) * HEADS + h];
      pre[itt] = *(const float4*)&conv[((size_t)b * NUM + j) * CH + h * DK + c4 * 4];
    }
  };
  // --- convert + write staged regs into LDS buffer ---
  auto lwrite = [&](int buf) {
    #pragma unroll
    for (int itt = 0; itt < 4; ++itt) {
      int j = jr + itt * 16;
      Cv[buf][c4 * 4 + 0][j] = tobf(pre[itt].x * psc[itt]);
      Cv[buf][c4 * 4 + 1][j] = tobf(pre[itt].y * psc[itt]);
      Cv[buf][c4 * 4 + 2][j] = tobf(pre[itt].z * psc[itt]);
      Cv[buf][c4 * 4 + 3][j] = tobf(pre[itt].w * psc[itt]);
    }
  };

  issue(0); lwrite(0);
  short8 a0 = *(const short8*)&wsin[wsrow + quad * 8];
  short8 a1 = *(const short8*)&wsin[wsrow + 32 + quad * 8];

  for (int jt = 0; jt < 4; ++jt) {
    const int cur = jt & 1;
    short8 na0, na1;
    if (jt < 3) {
      issue(jt + 1);   // global loads in flight across the MFMA phase
      na0 = *(const short8*)&wsin[wsrow + (jt + 1) * 64 + quad * 8];
      na1 = *(const short8*)&wsin[wsrow + (jt + 1) * 64 + 32 + quad * 8];
    }
    __syncthreads();   // Cv[cur] fully written; prior readers of Cv[cur^1] done
    #pragma unroll
    for (int ct = 0; ct < 4; ++ct)
      om[ct] = __builtin_amdgcn_mfma_f32_16x16x32_bf16(
          a0, *(const short8*)&Cv[cur][ct * 16 + m][quad * 8], om[ct], 0, 0, 0);
    #pragma unroll
    for (int ct = 0; ct < 4; ++ct)
      om[ct] = __builtin_amdgcn_mfma_f32_16x16x32_bf16(
          a1, *(const short8*)&Cv[cur][ct * 16 + m][32 + quad * 8], om[ct], 0, 0, 0);
    if (jt < 3) { lwrite(cur ^ 1); a0 = na0; a1 = na1; }
  }

  // plain stores into this jc's disjoint partial slice (no atomics, no RMW)
  const size_t ob = (size_t)(jc * B_ + b) * NUM;
  #pragma unroll
  for (int ct = 0; ct < 4; ++ct)
    #pragma unroll
    for (int r = 0; r < 4; ++r) {
      size_t idx = (ob + i0 + w * 16 + quad * 4 + r) * CH + h * DK + ct * 16 + m;
      outp[idx] = om[ct][r] * rni4[r];
    }
}

// ---------------- LayerNorm + final outputs (in-place on d_out regions) ----------------
__global__ __launch_bounds__(256) void final_kernel(
    float* __restrict__ ybnf, float* __restrict__ out0,
    const float* __restrict__ lnw, const float* __restrict__ lnb,
    const float* __restrict__ parts) {
  __shared__ float r1[4];
  __shared__ float r2[4];
  int bn = blockIdx.x;
  int c = threadIdx.x;
  size_t idx = (size_t)bn * CH + c;
  float y = ybnf[idx] + parts[idx] + parts[SEG_ + idx]
          + parts[2 * SEG_ + idx] + parts[3 * SEG_ + idx];
  float x2v = out0[idx];
  float s = y;
  #pragma unroll
  for (int off = 32; off; off >>= 1) s += __shfl_down(s, off, 64);
  int wave = c >> 6, lane = c & 63;
  if (lane == 0) r1[wave] = s;
  __syncthreads();
  float mu = (r1[0] + r1[1] + r1[2] + r1[3]) * (1.f / 256.f);
  float d = y - mu;
  float s2 = d * d;
  #pragma unroll
  for (int off = 32; off; off >>= 1) s2 += __shfl_down(s2, off, 64);
  if (lane == 0) r2[wave] = s2;
  __syncthreads();
  float var = (r2[0] + r2[1] + r2[2] + r2[3]) * (1.f / 256.f);
  float nf = d * rsqrtf(var + 1e-6f) * lnw[c] + lnb[c];
  ybnf[idx] = nf;
  out0[idx] = x2v + nf;
}

extern "C" void kernel_launch(void* const* d_in, const int* in_sizes, int n_in,
                              void* d_out, int out_size, void* d_ws, size_t ws_size,
                              hipStream_t stream) {
  const float* input = (const float*)d_in[0];
  const int* mroi = (const int*)d_in[1];
  const int* smask = (const int*)d_in[2];
  const float* gt_feat = (const float*)d_in[3];
  const float* w1 = (const float*)d_in[4];
  const float* b1 = (const float*)d_in[5];
  const float* w2 = (const float*)d_in[6];
  const float* b2 = (const float*)d_in[7];
  const float* gt_w = (const float*)d_in[8];
  const float* gt_b = (const float*)d_in[9];
  const float* lnw = (const float*)d_in[10];
  const float* lnb = (const float*)d_in[11];

  const size_t SEG = SEG_;         // 1048576 elements
  float* out0 = (float*)d_out;     // finally: out2^T + node_feat ; interim: X2 (conv2)
  float* gts = out0 + SEG;         // gts output (final from the start)
  float* nfreg = out0 + 2 * SEG;   // finally: node_feat ; interim: X1 then Yb

  // ws: F1 4MB | RN 64KB | VEC 8KB | candK 8MB | PK 512KB | XBF 2MB | WS 32MB | P 16MB
  float* F1 = (float*)d_ws;
  float* RN = F1 + SEG;
  float* VEC1 = RN + (size_t)B_ * NUM * HEADS;
  float* VEC2 = VEC1 + NUM;
  const size_t NCAND = (size_t)B_ * HEADS * 16 * NJC * 64 * 4;
  u64* candK = (u64*)(VEC2 + NUM);
  u64* PK = candK + NCAND;
  bf* XBF = (bf*)(PK + (size_t)B_ * NUM * 16);  // bf16 copy of stage input
  bf* WSC = XBF + SEG;                          // masked relu scores [b][h][i][j] bf16
  float* P = (float*)(WSC + (size_t)B_ * HEADS * NUM * NUM);  // 4 x SEG pv partials

  float* X1 = nfreg;  // conv1 output (F1 seeded = X1*(1+0.25*[sm==0]))
  float* X2 = out0;   // conv2 output lives in out0 region until final_kernel
  float* Yb = nfreg;  // o2m seed accumulator (= 0.25*[sm==0]*X2, overwrites dead X1)

  // fused: conv1+xbf (y<4) + gts (y 4..7) + pack/vec-zero (y 8..23)
  head_kernel<<<dim3(64, 24), 256, 0, stream>>>(
      input, w1, b1, smask, X1, F1, RN, XBF,
      gt_feat, gt_w, gt_b, gts, mroi, PK, VEC1, VEC2);

  // stage 1: scores once -> scratch + candidates; merge -> vec; PV apply (4-way jc)
  score_topk_kernel<<<dim3(16 * NJC, HEADS, B_), 256, 0, stream>>>(
      XBF, RN, PK, WSC, candK);
  topk_merge_kernel<<<64, 256, 0, stream>>>(candK, VEC1);
  pv_kernel<<<dim3(16 * NJC, HEADS, B_), 256, 0, stream>>>(WSC, X1, RN, VEC1, P);

  // stage 2 (conv2 folds F1 + sum(P) at load; also refreshes XBF with bf16(out1))
  conv_kernel<<<dim3(64, 4), 256, 0, stream>>>(F1, P, w2, b2, smask, 0.0f, X2, Yb, RN, XBF);
  score_topk_kernel<<<dim3(16 * NJC, HEADS, B_), 256, 0, stream>>>(
      XBF, RN, PK, WSC, candK);
  topk_merge_kernel<<<64, 256, 0, stream>>>(candK, VEC2);
  pv_kernel<<<dim3(16 * NJC, HEADS, B_), 256, 0, stream>>>(WSC, X2, RN, VEC2, P);

  // final folds Yb + sum(P) before LayerNorm
  final_kernel<<<4096, 256, 0, stream>>>(Yb, X2, lnw, lnb, P);
}